// Round 4
// baseline (3124.598 us; speedup 1.0000x reference)
//
#include <hip/hip_runtime.h>
#include <math.h>

#define VOCAB 50257
#define HID   1024
#define G4    4096
#define LZD   128
#define CDD   32
#define SEQ   256

// ---------------- helpers ----------------
__device__ __forceinline__ float sigm(float x){ return 1.0f/(1.0f+expf(-x)); }

// JAX uniform(-0.99999994,1) bits -> sqrt(2)*erfinv (Giles poly, == XLA f32 ErfInv)
__device__ __forceinline__ float eps_from_bits(unsigned bits){
  float f = __uint_as_float((bits>>9) | 0x3F800000u) - 1.0f;   // [0,1)
  const float MINV = -0.99999994f;                             // nextafter(-1,0)
  float u = fmaxf(MINV, f*2.0f + MINV);                        // (hi-lo) rounds to 2.0f
  float w = -log1pf(-u*u);
  float p;
  if(w < 5.0f){
    w -= 2.5f;
    p =  2.81022636e-08f;
    p = fmaf(p,w, 3.43273939e-07f);
    p = fmaf(p,w,-3.5233877e-06f);
    p = fmaf(p,w,-4.39150654e-06f);
    p = fmaf(p,w, 0.00021858087f);
    p = fmaf(p,w,-0.00125372503f);
    p = fmaf(p,w,-0.00417768164f);
    p = fmaf(p,w, 0.246640727f);
    p = fmaf(p,w, 1.50140941f);
  }else{
    w = sqrtf(w) - 3.0f;
    p = -0.000200214257f;
    p = fmaf(p,w, 0.000100950558f);
    p = fmaf(p,w, 0.00134934322f);
    p = fmaf(p,w,-0.00367342844f);
    p = fmaf(p,w, 0.00573950773f);
    p = fmaf(p,w,-0.0076224613f);
    p = fmaf(p,w, 0.00943887047f);
    p = fmaf(p,w, 1.00167406f);
    p = fmaf(p,w, 2.83297682f);
  }
  return 1.4142135623730951f * (p*u);
}

// ---------------- gathers / init ----------------
__global__ __launch_bounds__(256) void embed_enc(
    const int* __restrict__ tok, const float* __restrict__ emb, float* __restrict__ x)
{
  const int b = blockIdx.x, tid = threadIdx.x;
  const int t = tok[b];
  float4 v = *(const float4*)(emb + (size_t)t*HID + tid*4);
  *(float4*)(x + (size_t)b*HID + tid*4) = v;
}

__global__ __launch_bounds__(256) void embed_dec(
    const int* __restrict__ tok, const float* __restrict__ emb, float* __restrict__ x)
{
  const int b = blockIdx.x, tid = threadIdx.x;
  const int t = (b==0) ? 0 : tok[b-1];   // SOS = 0
  float4 v = *(const float4*)(emb + (size_t)t*HID + tid*4);
  v.x=fmaxf(v.x,0.f); v.y=fmaxf(v.y,0.f); v.z=fmaxf(v.z,0.f); v.w=fmaxf(v.w,0.f);
  *(float4*)(x + (size_t)b*HID + tid*4) = v;
}

__global__ __launch_bounds__(256) void init_state(
    const float* __restrict__ h0, const float* __restrict__ c0,
    float* __restrict__ hb0, float* __restrict__ cbuf)
{
  const int tid = threadIdx.x;
  float4 h = *(const float4*)(h0 + tid*4); *(float4*)(hb0 + tid*4) = h;
  float4 c = *(const float4*)(c0 + tid*4); *(float4*)(cbuf + tid*4) = c;
}

// ---------------- fp32 GEMM: C[M,N] = A[M,K] @ B[N,K]^T + b1 (+ b2) ----------------
__global__ __launch_bounds__(256) void gemm_nt_bias(
    const float* __restrict__ A, const float* __restrict__ B,
    const float* __restrict__ bias1, const float* __restrict__ bias2,
    float* __restrict__ C, int K, int N)
{
  __shared__ float As[16*68];
  __shared__ float Bs[16*68];
  const int tid = threadIdx.x;
  const int bn = blockIdx.x<<6, bm = blockIdx.y<<6;
  const int lr = tid>>2, lc4 = (tid&3)<<2;
  const int tx = tid&15, ty = tid>>4;
  const float* Arow = A + (size_t)(bm+lr)*K + lc4;
  const float* Brow = B + (size_t)(bn+lr)*K + lc4;
  const bool bvalid = (bn+lr) < N;
  float acc[4][4] = {};
  for(int kt=0; kt<K; kt+=16){
    float4 av = *(const float4*)(Arow + kt);
    float4 bv = bvalid ? *(const float4*)(Brow + kt) : make_float4(0.f,0.f,0.f,0.f);
    __syncthreads();
    As[(lc4+0)*68+lr]=av.x; As[(lc4+1)*68+lr]=av.y; As[(lc4+2)*68+lr]=av.z; As[(lc4+3)*68+lr]=av.w;
    Bs[(lc4+0)*68+lr]=bv.x; Bs[(lc4+1)*68+lr]=bv.y; Bs[(lc4+2)*68+lr]=bv.z; Bs[(lc4+3)*68+lr]=bv.w;
    __syncthreads();
#pragma unroll
    for(int k=0;k<16;++k){
      float4 a = *(const float4*)(As + k*68 + (ty<<2));
      float4 b = *(const float4*)(Bs + k*68 + (tx<<2));
      float a4[4] = {a.x,a.y,a.z,a.w};
      float b4[4] = {b.x,b.y,b.z,b.w};
#pragma unroll
      for(int i=0;i<4;++i)
#pragma unroll
        for(int j=0;j<4;++j)
          acc[i][j] = fmaf(a4[i], b4[j], acc[i][j]);
    }
  }
  const int n0 = bn + (tx<<2);
#pragma unroll
  for(int i=0;i<4;++i){
    const int m = bm + (ty<<2) + i;
#pragma unroll
    for(int j=0;j<4;++j){
      const int n = n0+j;
      if(n < N)
        C[(size_t)m*N + n] = acc[i][j] + bias1[n] + (bias2 ? bias2[n] : 0.f);
    }
  }
}

// ---------------- one LSTM step: grid 128 WGs, WG b owns units 8b..8b+7 ----------------
__global__ __launch_bounds__(256) void lstm_step(
    const float* __restrict__ Whh, const float* __restrict__ pre_t,
    const float* __restrict__ h_in, float* __restrict__ h_out,
    float* __restrict__ cbuf, float* __restrict__ Hrow)
{
  __shared__ float h_lds[HID];
  __shared__ float gbuf[32];
  const int b = blockIdx.x, tid = threadIdx.x;
  const int r = tid>>3, l = tid&7;        // r: 32 gate-rows, l: 8-way K split
  for(int i=tid;i<HID;i+=256) h_lds[i] = h_in[i];
  __syncthreads();
  const int gate = r>>3, it = r&7;
  const float* wr = Whh + (size_t)(gate*HID + 8*b + it)*HID + l*4;
  const float* hr = h_lds + l*4;
  float a0=0,a1=0,a2=0,a3=0;
#pragma unroll 8
  for(int kk=0; kk<32; ++kk){
    float4 wv = *(const float4*)(wr + kk*32);
    float4 hv = *(const float4*)(hr + kk*32);
    a0 = fmaf(wv.x, hv.x, a0);
    a1 = fmaf(wv.y, hv.y, a1);
    a2 = fmaf(wv.z, hv.z, a2);
    a3 = fmaf(wv.w, hv.w, a3);
  }
  float acc = (a0+a1)+(a2+a3);
  acc += __shfl_xor(acc,1); acc += __shfl_xor(acc,2); acc += __shfl_xor(acc,4);
  if(l==0) gbuf[r] = acc + pre_t[gate*HID + 8*b + it];
  __syncthreads();
  if(tid<8){
    const int u = 8*b + tid;
    float gi=gbuf[tid], gf=gbuf[8+tid], gg=gbuf[16+tid], go=gbuf[24+tid];
    float c = cbuf[u];
    float cn = sigm(gf)*c + sigm(gi)*tanhf(gg);
    float hn = sigm(go)*tanhf(cn);
    cbuf[u] = cn;
    h_out[u] = hn;
    if(Hrow) Hrow[u] = hn;
  }
}

// ---------------- mean/logvar rows (grid 256: rows 0..127 mean, 128..255 logvar) ----------------
__global__ __launch_bounds__(256) void mean_logvar(
    const float* __restrict__ henc,
    const float* __restrict__ mean_W, const float* __restrict__ mean_b,
    const float* __restrict__ logvar_W, const float* __restrict__ logvar_b,
    float* __restrict__ meanlv, float* __restrict__ out_mean, float* __restrict__ out_lv)
{
  __shared__ float redb[4];
  const int row = blockIdx.x, tid = threadIdx.x;
  const float* Wrow = (row < LZD) ? (mean_W + (size_t)row*HID)
                                  : (logvar_W + (size_t)(row-LZD)*HID);
  const float bias = (row < LZD) ? mean_b[row] : logvar_b[row-LZD];
  float4 hv = *(const float4*)(henc + tid*4);
  float4 wv = *(const float4*)(Wrow + tid*4);
  float p = hv.x*wv.x + hv.y*wv.y + hv.z*wv.z + hv.w*wv.w;
  p += __shfl_xor(p,1); p += __shfl_xor(p,2); p += __shfl_xor(p,4);
  p += __shfl_xor(p,8); p += __shfl_xor(p,16); p += __shfl_xor(p,32);
  if((tid&63)==0) redb[tid>>6] = p;
  __syncthreads();
  if(tid==0){
    float s = redb[0]+redb[1]+redb[2]+redb[3] + bias;
    meanlv[row] = s;
    if(row < LZD) out_mean[row] = s; else out_lv[row-LZD] = s;
  }
}

// ---------------- eps (PARTITIONABLE threefry, key=1) + latent + dec_h init ----------------
// JAX jax_threefry_partitionable=True (modern default): per element i, apply the
// threefry2x32 permutation to counter (hi,lo)=(0,i); 32-bit output = word0 ^ word1.
__global__ __launch_bounds__(256) void latent_dech(
    const float* __restrict__ meanlv, const float* __restrict__ ccond,
    const float* __restrict__ lc_W, const float* __restrict__ lc_b,
    float* __restrict__ hb0, float* __restrict__ cbuf)
{
  __shared__ float eps[LZD];
  __shared__ float lat[LZD+CDD];
  const int tid = threadIdx.x;
  if(tid < LZD){
    unsigned x0 = 0u;                 // hi32 of 64-bit counter i
    unsigned x1 = (unsigned)tid;      // lo32
    const unsigned ks[3] = {0u, 1u, 0x1BD11BDAu ^ 0u ^ 1u};   // key(1) -> (0,1)
    x0 += ks[0]; x1 += ks[1];
    const int RA[4] = {13,15,26,6}, RB[4] = {17,29,16,24};
#pragma unroll
    for(int g=0; g<5; ++g){
      const int* R = (g&1) ? RB : RA;
#pragma unroll
      for(int q=0;q<4;++q){
        x0 += x1;
        x1 = (x1 << R[q]) | (x1 >> (32-R[q]));
        x1 ^= x0;
      }
      x0 += ks[(g+1)%3];
      x1 += ks[(g+2)%3] + (unsigned)(g+1);
    }
    eps[tid] = eps_from_bits(x0 ^ x1);
  }
  __syncthreads();
  if(tid < LZD){
    lat[tid] = fmaf(eps[tid], expf(0.5f*meanlv[LZD+tid]), meanlv[tid]);
  } else if(tid < LZD+CDD){
    lat[tid] = ccond[tid-LZD];
  }
  __syncthreads();
  for(int u=tid; u<HID; u+=256){
    float s = 0.f;
    const float* wr = lc_W + (size_t)u*(LZD+CDD);
#pragma unroll 8
    for(int k=0;k<LZD+CDD;++k) s = fmaf(lat[k], wr[k], s);
    hb0[u] = s + lc_b[u];
    cbuf[u] = 0.0f;
  }
}

// ---------------- in-place log_softmax + first-index argmax ----------------
__global__ __launch_bounds__(256) void softmax_argmax(float* __restrict__ dist,
                                                      float* __restrict__ outTok)
{
  __shared__ float wm[4]; __shared__ int wi[4];
  __shared__ float s_max; __shared__ int s_idx; __shared__ float s_lz;
  const int t = blockIdx.x, tid = threadIdx.x;
  float* row = dist + (size_t)t*VOCAB;
  float m = -INFINITY; int idx = VOCAB;
  for(int i=tid; i<VOCAB; i+=256){
    float v = row[i];
    if(v > m){ m = v; idx = i; }
  }
  for(int d=1; d<64; d<<=1){
    float m2 = __shfl_xor(m, d); int i2 = __shfl_xor(idx, d);
    if(m2 > m || (m2 == m && i2 < idx)){ m = m2; idx = i2; }
  }
  if((tid&63)==0){ wm[tid>>6]=m; wi[tid>>6]=idx; }
  __syncthreads();
  if(tid==0){
    float mm = wm[0]; int ii = wi[0];
    for(int q=1;q<4;++q) if(wm[q]>mm || (wm[q]==mm && wi[q]<ii)){ mm=wm[q]; ii=wi[q]; }
    s_max = mm; s_idx = ii;
  }
  __syncthreads();
  const float M = s_max;
  float s = 0.f;
  for(int i=tid; i<VOCAB; i+=256) s += expf(row[i] - M);
  for(int d=1; d<64; d<<=1) s += __shfl_xor(s, d);
  if((tid&63)==0) wm[tid>>6] = s;
  __syncthreads();
  if(tid==0) s_lz = M + logf(wm[0]+wm[1]+wm[2]+wm[3]);
  __syncthreads();
  const float lz = s_lz;
  for(int i=tid; i<VOCAB; i+=256) row[i] -= lz;
  if(tid==0) outTok[t] = (float)s_idx;
}

// ---------------- launch ----------------
extern "C" void kernel_launch(void* const* d_in, const int* in_sizes, int n_in,
                              void* d_out, int out_size, void* d_ws, size_t ws_size,
                              hipStream_t stream)
{
  (void)in_sizes; (void)n_in; (void)out_size; (void)ws_size;
  const int*   tok      = (const int*)  d_in[0];
  const float* h0       = (const float*)d_in[1];
  const float* c0       = (const float*)d_in[2];
  const float* ccond    = (const float*)d_in[3];
  // d_in[4] = use_teacher_forcing (unused by reference body)
  const float* enc_emb  = (const float*)d_in[5];
  const float* enc_Wih  = (const float*)d_in[6];
  const float* enc_Whh  = (const float*)d_in[7];
  const float* enc_bih  = (const float*)d_in[8];
  const float* enc_bhh  = (const float*)d_in[9];
  const float* dec_emb  = (const float*)d_in[10];
  const float* dec_Wih  = (const float*)d_in[11];
  const float* dec_Whh  = (const float*)d_in[12];
  const float* dec_bih  = (const float*)d_in[13];
  const float* dec_bhh  = (const float*)d_in[14];
  const float* out_W    = (const float*)d_in[15];
  const float* out_b    = (const float*)d_in[16];
  const float* mean_W   = (const float*)d_in[17];
  const float* mean_b   = (const float*)d_in[18];
  const float* logvar_W = (const float*)d_in[19];
  const float* logvar_b = (const float*)d_in[20];
  const float* lc_W     = (const float*)d_in[21];
  const float* lc_b     = (const float*)d_in[22];

  float* ws     = (float*)d_ws;
  float* xbuf   = ws;                        // 256*1024  (reused enc then dec)
  float* pre    = xbuf + (size_t)SEQ*HID;    // 256*4096  (reused enc then dec)
  float* hb     = pre + (size_t)SEQ*G4;      // 2*1024 ping-pong h
  float* cbuf   = hb + 2*HID;                // 1024
  float* Hdec   = cbuf + HID;                // 256*1024
  float* meanlv = Hdec + (size_t)SEQ*HID;    // 256
  // total ~6.3 MB

  float* out      = (float*)d_out;
  float* outTok   = out;                          // [256] tokens (as f32)
  float* dist     = out + SEQ;                    // [256,50257] log-softmax
  float* out_mean = dist + (size_t)SEQ*VOCAB;     // [128]
  float* out_lv   = out_mean + LZD;               // [128]

  // encoder phase
  hipLaunchKernelGGL(embed_enc, dim3(SEQ), dim3(256), 0, stream, tok, enc_emb, xbuf);
  hipLaunchKernelGGL(gemm_nt_bias, dim3(G4/64, SEQ/64), dim3(256), 0, stream,
                     xbuf, enc_Wih, enc_bih, enc_bhh, pre, HID, G4);
  hipLaunchKernelGGL(init_state, dim3(1), dim3(256), 0, stream, h0, c0, hb, cbuf);
  for(int t=0; t<SEQ; ++t){
    hipLaunchKernelGGL(lstm_step, dim3(128), dim3(256), 0, stream,
                       enc_Whh, pre + (size_t)t*G4,
                       hb + (t&1)*HID, hb + ((t+1)&1)*HID, cbuf, (float*)nullptr);
  }
  hipLaunchKernelGGL(mean_logvar, dim3(2*LZD), dim3(256), 0, stream,
                     hb /* final enc h in slot 0 */,
                     mean_W, mean_b, logvar_W, logvar_b, meanlv, out_mean, out_lv);

  // decoder phase (reuse xbuf/pre)
  hipLaunchKernelGGL(embed_dec, dim3(SEQ), dim3(256), 0, stream, tok, dec_emb, xbuf);
  hipLaunchKernelGGL(gemm_nt_bias, dim3(G4/64, SEQ/64), dim3(256), 0, stream,
                     xbuf, dec_Wih, dec_bih, dec_bhh, pre, HID, G4);
  hipLaunchKernelGGL(latent_dech, dim3(1), dim3(256), 0, stream,
                     meanlv, ccond, lc_W, lc_b, hb /* slot 0 */, cbuf);
  for(int t=0; t<SEQ; ++t){
    hipLaunchKernelGGL(lstm_step, dim3(128), dim3(256), 0, stream,
                       dec_Whh, pre + (size_t)t*G4,
                       hb + (t&1)*HID, hb + ((t+1)&1)*HID, cbuf, Hdec + (size_t)t*HID);
  }

  // logits + log-softmax + argmax
  hipLaunchKernelGGL(gemm_nt_bias, dim3((VOCAB+63)/64, SEQ/64), dim3(256), 0, stream,
                     Hdec, out_W, out_b, (const float*)nullptr, dist, HID, VOCAB);
  hipLaunchKernelGGL(softmax_argmax, dim3(SEQ), dim3(256), 0, stream, dist, outTok);
}